// Round 7
// baseline (334.689 us; speedup 1.0000x reference)
//
#include <hip/hip_runtime.h>
#include <hip/hip_bf16.h>
#include <stdint.h>

// GroupCommunication fused: 65536 tok x 1024 ch; 16 blocks x 64; 2 heads x 32.
// Base = R4 (best: 64KB LDS, 4 barriers, 2 WGs/CU). Two changes:
//  1) lgkm-only barriers (s_waitcnt lgkmcnt(0) + raw s_barrier) so wfrag
//     global loads survive across barriers (no vmcnt(0) drain).
//  2) wfrag loads batched into static-indexed arrays issued at phase top
//     (fq/fk/fv per PH1; ff for PH3 issued one phase early) -> L2 latency
//     hidden under MFMA + barrier instead of serial 200cy stalls per pair.
// Schedule: PH1(0)+LOADF(0)+accinit |B| PH2 |B| PH3(0)+PH1(1)+LOADF(1) |B|
//           PH2 |B| PH3(1)+store.

typedef __attribute__((ext_vector_type(8))) short bf16x8;
typedef __attribute__((ext_vector_type(4))) float f32x4;

#define NTOK   65536
#define DM     1024
#define TT     16
#define QSCALE 0.17677669529663687f    // 32^-0.5
#define LOG2E  1.4426950408889634f

// lgkm-only barrier: DS ordering across waves, global loads stay in flight.
#define WG_BARRIER() do {                                   \
  asm volatile("s_waitcnt lgkmcnt(0)" ::: "memory");        \
  __builtin_amdgcn_s_barrier();                             \
} while (0)

static __device__ __forceinline__ unsigned short f2bf(float f) {
  union { __hip_bfloat16 h; unsigned short s; } cv;
  cv.h = __float2bfloat16(f);          // RNE
  return cv.s;
}

static __device__ __forceinline__ unsigned int pk2(float a, float b) {
  return (unsigned int)f2bf(a) | ((unsigned int)f2bf(b) << 16);
}

static __device__ __forceinline__ bf16x8 pack8(float4 a, float4 b) {
  bf16x8 r;
  r[0] = (short)f2bf(a.x); r[1] = (short)f2bf(a.y);
  r[2] = (short)f2bf(a.z); r[3] = (short)f2bf(a.w);
  r[4] = (short)f2bf(b.x); r[5] = (short)f2bf(b.y);
  r[6] = (short)f2bf(b.z); r[7] = (short)f2bf(b.w);
  return r;
}

union FragCast { uint4 u4; bf16x8 v; uint2 u2[2]; unsigned int u[4]; };

// ---------------------------------------------------------------------------
// Prologue: pack wq(scaled),wk,wv,wf fp32 [g][i][o] -> bf16 fragment stream.
// frag elem j = W[k = kk*32 + 8*(lane>>4) + j][o = nf*16 + (lane&15)].
// A- and B-side consumers always use the identical (lane,j)->k map, so any
// HW k-permutation cancels.
// ---------------------------------------------------------------------------
__global__ void build_wfrag(const float* __restrict__ wq, const float* __restrict__ wk,
                            const float* __restrict__ wv, const float* __restrict__ wf,
                            uint4* __restrict__ wfrag) {
  int tid = blockIdx.x * 256 + threadIdx.x;
  if (tid >= 4 * 16 * 2 * 4 * 64) return;
  int lane =  tid        & 63;
  int nf   = (tid >> 6)  & 3;
  int kk   = (tid >> 8)  & 1;
  int g    = (tid >> 9)  & 15;
  int mat  =  tid >> 13;
  const float* w = (mat == 0) ? wq : (mat == 1) ? wk : (mat == 2) ? wv : wf;
  float sc = (mat == 0) ? QSCALE : 1.0f;
  int o  = nf * 16 + (lane & 15);
  int kb = kk * 32 + 8 * (lane >> 4);
  unsigned int packed[4];
#pragma unroll
  for (int jj = 0; jj < 4; ++jj) {
    unsigned short lo = f2bf(w[(g * 64 + kb + 2 * jj    ) * 64 + o] * sc);
    unsigned short hi = f2bf(w[(g * 64 + kb + 2 * jj + 1) * 64 + o] * sc);
    packed[jj] = (unsigned int)lo | ((unsigned int)hi << 16);
  }
  uint4 u; u.x = packed[0]; u.y = packed[1]; u.z = packed[2]; u.w = packed[3];
  wfrag[tid] = u;
}

// ---------------------------------------------------------------------------
// Phase macros (textual expansion; h_ must be a literal 0/1).
// Load batching: all wfrag loads of a phase go through static-indexed local
// arrays declared at the top so the scheduler can issue them early (bounded
// by the 128-VGPR cap) and the MFMAs drain them with precise vmcnt waits.
// ---------------------------------------------------------------------------
#define PH1(h_) do {                                                          \
  FragCast fq[8], fk[8], fv[8];                                               \
  _Pragma("unroll")                                                           \
  for (int gi = 0; gi < 2; ++gi) {                                            \
    const int g = 2 * w + gi;                                                 \
    _Pragma("unroll")                                                         \
    for (int kk = 0; kk < 2; ++kk) {                                          \
      _Pragma("unroll")                                                       \
      for (int nf2 = 0; nf2 < 2; ++nf2) {                                     \
        const int nf = 2 * (h_) + nf2;                                        \
        const int ix = gi * 4 + kk * 2 + nf2;                                 \
        fq[ix].u4 = wfrag[(((0 * 16 + g) * 2 + kk) * 4 + nf) * 64 + lane];    \
        fk[ix].u4 = wfrag[(((1 * 16 + g) * 2 + kk) * 4 + nf) * 64 + lane];    \
        fv[ix].u4 = wfrag[(((2 * 16 + g) * 2 + kk) * 4 + nf) * 64 + lane];    \
      }                                                                       \
    }                                                                         \
  }                                                                           \
  _Pragma("unroll")                                                           \
  for (int mat = 0; mat < 2; ++mat) {      /* q, k (swapped orientation) */   \
    const float* bp = mat ? bk : bq;                                          \
    const float bsc = mat ? 1.0f : QSCALE;                                    \
    unsigned short* dst = mat ? s_k : s_q;                                    \
    _Pragma("unroll")                                                         \
    for (int gi = 0; gi < 2; ++gi) {                                          \
      const int g = 2 * w + gi;                                               \
      _Pragma("unroll")                                                       \
      for (int nf2 = 0; nf2 < 2; ++nf2) {                                     \
        const int nf = 2 * (h_) + nf2;                                        \
        float4 b4 = *(const float4*)&bp[g * 64 + nf * 16 + 4 * lq];           \
        f32x4 a1 = {b4.x * bsc, b4.y * bsc, b4.z * bsc, b4.w * bsc};          \
        _Pragma("unroll")                                                     \
        for (int kk = 0; kk < 2; ++kk) {                                      \
          a1 = __builtin_amdgcn_mfma_f32_16x16x32_bf16(                       \
              (mat ? fk : fq)[gi * 4 + kk * 2 + nf2].v, afr[gi][kk], a1,      \
              0, 0, 0);                                                       \
        }                                                                     \
        /* D[o][t]: col t=lr, rows o=nf*16+4lq+r -> d_h = nf2*16+4lq+r */     \
        uint2 w2; w2.x = pk2(a1[0], a1[1]); w2.y = pk2(a1[2], a1[3]);         \
        const int blk = (16 * (2 * nf2 + (lq >> 1)) + g) ^ (lr & 7);          \
        *(uint2*)&dst[lr * 512 + blk * 8 + 4 * (lq & 1)] = w2;                \
      }                                                                       \
    }                                                                         \
  }                                                                           \
  _Pragma("unroll")                                                           \
  for (int gi = 0; gi < 2; ++gi) {         /* v (original orientation) */     \
    const int g = 2 * w + gi;                                                 \
    _Pragma("unroll")                                                         \
    for (int nf2 = 0; nf2 < 2; ++nf2) {                                       \
      const int nf = 2 * (h_) + nf2;                                          \
      const float bias = bv[g * 64 + nf * 16 + lr];                           \
      f32x4 a1 = {bias, bias, bias, bias};                                    \
      _Pragma("unroll")                                                       \
      for (int kk = 0; kk < 2; ++kk) {                                        \
        a1 = __builtin_amdgcn_mfma_f32_16x16x32_bf16(                         \
            afr[gi][kk], fv[gi * 4 + kk * 2 + nf2].v, a1, 0, 0, 0);           \
      }                                                                       \
      /* D[t][o]: col o (d_h = nf2*16+lr), rows t=4lq+r; f = g */             \
      const int L = 16 * (g >> 2) + lr;                                       \
      const int jj = g & 3;                                                   \
      _Pragma("unroll")                                                       \
      for (int r = 0; r < 4; ++r)                                             \
        s_v[((4 * lq + r) * 2 + nf2) * 256 + L * 4 + jj] = f2bf(a1[r]);       \
    }                                                                         \
  }                                                                           \
} while (0)

#define LOADF(h_) do {                                                        \
  _Pragma("unroll")                                                           \
  for (int gi = 0; gi < 2; ++gi) {                                            \
    const int g = 2 * w + gi;                                                 \
    _Pragma("unroll")                                                         \
    for (int nf = 0; nf < 4; ++nf)                                            \
      ff[gi * 4 + nf].u4 = wfrag[(((3 * 16 + g) * 2 + (h_)) * 4 + nf) * 64 + lane]; \
  }                                                                           \
} while (0)

#define PH2() do {                                                            \
  _Pragma("unroll")                                                           \
  for (int tt = 0; tt < 2; ++tt) {                                            \
    const int t = 2 * w + tt;                                                 \
    f32x4 zero = {0.f, 0.f, 0.f, 0.f};                                        \
    FragCast qa, ka;                                                          \
    const int blk = lane ^ (t & 7);                                           \
    qa.u4 = *(const uint4*)&s_q[t * 512 + blk * 8];                           \
    ka.u4 = *(const uint4*)&s_k[t * 512 + blk * 8];                           \
    /* D[f][g]: col g=lr, rows f=4lq+r (K=32 = full head dim) */              \
    f32x4 sc4 = __builtin_amdgcn_mfma_f32_16x16x32_bf16(ka.v, qa.v, zero, 0, 0, 0); \
    float m = fmaxf(fmaxf(sc4[0], sc4[1]), fmaxf(sc4[2], sc4[3]));            \
    m = fmaxf(m, __shfl_xor(m, 16));                                          \
    m = fmaxf(m, __shfl_xor(m, 32));                                          \
    float p0 = exp2f((sc4[0] - m) * LOG2E);                                   \
    float p1 = exp2f((sc4[1] - m) * LOG2E);                                   \
    float p2 = exp2f((sc4[2] - m) * LOG2E);                                   \
    float p3 = exp2f((sc4[3] - m) * LOG2E);                                   \
    float s = p0 + p1 + p2 + p3;                                              \
    s += __shfl_xor(s, 16);                                                   \
    s += __shfl_xor(s, 32);                                                   \
    const float inv = __fdividef(1.0f, s);                                    \
    FragCast pa;               /* P[g=lr][f=4lq+jj] at slots jj 0..3 */       \
    pa.u[0] = pk2(p0 * inv, p1 * inv);                                        \
    pa.u[1] = pk2(p2 * inv, p3 * inv);                                        \
    pa.u[2] = 0; pa.u[3] = 0;                                                 \
    _Pragma("unroll")                                                         \
    for (int nf = 0; nf < 2; ++nf) {                                          \
      FragCast va;             /* V[f=4lq+jj][d=nf*16+lr] at slots jj 0..3 */ \
      va.u2[0] = *(const uint2*)&s_v[(t * 2 + nf) * 256 + lane * 4];          \
      va.u[2] = 0; va.u[3] = 0;                                               \
      f32x4 o4 = __builtin_amdgcn_mfma_f32_16x16x32_bf16(va.v, pa.v, zero, 0, 0, 0); \
      /* D[d][g]: col g=lr, rows d=nf*16+4lq+r */                             \
      uint2 w2; w2.x = pk2(o4[0], o4[1]); w2.y = pk2(o4[2], o4[3]);           \
      const int ablk = (16 * (2 * nf + (lq >> 1)) + lr) ^ (t & 7);            \
      *(uint2*)&s_att[t * 512 + ablk * 8 + 4 * (lq & 1)] = w2;                \
    }                                                                         \
  }                                                                           \
} while (0)

#define PH3() do {                                                            \
  _Pragma("unroll")                                                           \
  for (int gi = 0; gi < 2; ++gi) {                                            \
    const int g = 2 * w + gi;                                                 \
    FragCast aa;               /* att[t=lr][g][d=8lq+j] -> B[k][t] */         \
    const int blk = (16 * lq + g) ^ (lr & 7);                                 \
    aa.u4 = *(const uint4*)&s_att[lr * 512 + blk * 8];                        \
    _Pragma("unroll")                                                         \
    for (int nf = 0; nf < 4; ++nf) {                                          \
      acc[gi][nf] = __builtin_amdgcn_mfma_f32_16x16x32_bf16(                  \
          ff[gi * 4 + nf].v, aa.v, acc[gi][nf], 0, 0, 0);                     \
    }                                                                         \
  }                                                                           \
} while (0)

// ---------------------------------------------------------------------------
__global__ __launch_bounds__(512, 4)
void fused_gc(const float* __restrict__ x,
              const float* __restrict__ bq, const float* __restrict__ bk,
              const float* __restrict__ bv, const float* __restrict__ bfb,
              const uint4* __restrict__ wfrag,
              float* __restrict__ out) {
  // Per-head fragment streams: [t(16)][blk(64)] x 16B. frag(t,L) holds
  // M[t][c = L&15][d = 8*(L>>4)+j]; stored at blk = L ^ (t&7).   16KB each.
  __shared__ __align__(16) unsigned short s_q  [16 * 512];
  __shared__ __align__(16) unsigned short s_k  [16 * 512];
  __shared__ __align__(16) unsigned short s_att[16 * 512];
  // v stream: [t][nf(2)][L(64)] x 4 shorts; frag = V[f=4*(L>>4)+jj][d=nf*16+(L&15)]
  __shared__ __align__(16) unsigned short s_v  [16 * 2 * 64 * 4];

  const int tid  = threadIdx.x;
  const int w    = tid >> 6;      // 8 waves; g = 2w+gi, t = 2w+tt
  const int lane = tid & 63;
  const int lr   = lane & 15;
  const int lq   = lane >> 4;
  const long tok0 = (long)blockIdx.x * TT;

  // x fragments for this tile: lane's token row = lr
  bf16x8 afr[2][2];
  {
    const float* xr = x + (tok0 + lr) * DM;
#pragma unroll
    for (int gi = 0; gi < 2; ++gi) {
      const int g = 2 * w + gi;
#pragma unroll
      for (int kk = 0; kk < 2; ++kk) {
        const float* p = xr + g * 64 + kk * 32 + 8 * lq;
        afr[gi][kk] = pack8(*(const float4*)p, *(const float4*)(p + 4));
      }
    }
  }

  f32x4 acc[2][4];                // [gi][nf] final-linear accumulators
  FragCast ff[8];                 // PH3 weight frags, loaded a phase early

  PH1(0);
  LOADF(0);                       // in flight across barrier + PH2
  // acc init with final bias (loads issue here, consumed in PH3)
#pragma unroll
  for (int gi = 0; gi < 2; ++gi) {
    const int g = 2 * w + gi;
#pragma unroll
    for (int nf = 0; nf < 4; ++nf) {
      float4 b4 = *(const float4*)&bfb[g * 64 + nf * 16 + 4 * lq];
      acc[gi][nf][0] = b4.x; acc[gi][nf][1] = b4.y;
      acc[gi][nf][2] = b4.z; acc[gi][nf][3] = b4.w;
    }
  }
  WG_BARRIER();
  PH2();
  WG_BARRIER();
  PH3();                          // consumes ff(h0)
  PH1(1);
  LOADF(1);                       // in flight across barrier + PH2
  WG_BARRIER();
  PH2();
  WG_BARRIER();
  PH3();                          // consumes ff(h1)

  // store out: D[o][t] -> one float4 per nf
#pragma unroll
  for (int gi = 0; gi < 2; ++gi) {
    const int g = 2 * w + gi;
#pragma unroll
    for (int nf = 0; nf < 4; ++nf) {
      float4 o4;
      o4.x = acc[gi][nf][0]; o4.y = acc[gi][nf][1];
      o4.z = acc[gi][nf][2]; o4.w = acc[gi][nf][3];
      *(float4*)&out[(tok0 + lr) * DM + g * 64 + nf * 16 + 4 * lq] = o4;
    }
  }
}

// ---------------------------------------------------------------------------
extern "C" void kernel_launch(void* const* d_in, const int* in_sizes, int n_in,
                              void* d_out, int out_size, void* d_ws, size_t ws_size,
                              hipStream_t stream) {
  const float* x   = (const float*)d_in[0];
  const float* wq  = (const float*)d_in[1];
  const float* bq_ = (const float*)d_in[2];
  const float* wk  = (const float*)d_in[3];
  const float* bk_ = (const float*)d_in[4];
  const float* wv  = (const float*)d_in[5];
  const float* bv_ = (const float*)d_in[6];
  const float* wf  = (const float*)d_in[7];
  const float* bf_ = (const float*)d_in[8];
  (void)in_sizes; (void)n_in; (void)out_size; (void)ws_size;

  uint4* wfrag = (uint4*)d_ws;   // 4*16*2*4*64 frags * 16B = 512 KiB

  build_wfrag<<<128, 256, 0, stream>>>(wq, wk, wv, wf, wfrag);
  fused_gc<<<NTOK / TT, 512, 0, stream>>>(x, bq_, bk_, bv_, bf_, wfrag,
                                          (float*)d_out);
}

// Round 8
// 292.036 us; speedup vs baseline: 1.1461x; 1.1461x over previous
//
#include <hip/hip_runtime.h>
#include <hip/hip_bf16.h>
#include <stdint.h>

// GroupCommunication fused: 65536 tok x 1024 ch; 16 blocks x 64; 2 heads x 32.
// R8: two-kernel split. K1 = QKV+attention, att written from PH2 registers
// straight to a global fragment buffer (no s_att, no PH3, 3 barriers, 48KB
// LDS). K2 = final grouped GEMM, barrier-free/LDS-free streaming (HBM-bound).
// If ws_size can't hold the 128MB att buffer, fall back to the fused R4
// schedule (template SPLIT=0).
// Weight regions in wfrag: mat 0..3 = q,k,v,f with k-map k=kk*32+8*(L>>4)+j
// (fused PH3 uses mat 3); mat 4 = f with K2's k-map k=kk*32+4*(L>>4)+(j&3)
// +16*(j>>2), which matches what PH2's D-register layout can store
// contiguously. A/B sides of every MFMA share the same (lane,j)->k map.

typedef __attribute__((ext_vector_type(8))) short bf16x8;
typedef __attribute__((ext_vector_type(4))) float f32x4;

#define NTOK   65536
#define DM     1024
#define TT     16
#define QSCALE 0.17677669529663687f    // 32^-0.5
#define LOG2E  1.4426950408889634f

static __device__ __forceinline__ unsigned short f2bf(float f) {
  union { __hip_bfloat16 h; unsigned short s; } cv;
  cv.h = __float2bfloat16(f);          // RNE
  return cv.s;
}

static __device__ __forceinline__ unsigned int pk2(float a, float b) {
  return (unsigned int)f2bf(a) | ((unsigned int)f2bf(b) << 16);
}

static __device__ __forceinline__ bf16x8 pack8(float4 a, float4 b) {
  bf16x8 r;
  r[0] = (short)f2bf(a.x); r[1] = (short)f2bf(a.y);
  r[2] = (short)f2bf(a.z); r[3] = (short)f2bf(a.w);
  r[4] = (short)f2bf(b.x); r[5] = (short)f2bf(b.y);
  r[6] = (short)f2bf(b.z); r[7] = (short)f2bf(b.w);
  return r;
}

union FragCast { uint4 u4; bf16x8 v; uint2 u2[2]; unsigned int u[4]; };

// ---------------------------------------------------------------------------
// Prologue: pack weights -> bf16 fragment stream (5 regions, see header).
// ---------------------------------------------------------------------------
__global__ void build_wfrag(const float* __restrict__ wq, const float* __restrict__ wk,
                            const float* __restrict__ wv, const float* __restrict__ wf,
                            uint4* __restrict__ wfrag) {
  int tid = blockIdx.x * 256 + threadIdx.x;
  if (tid >= 5 * 16 * 2 * 4 * 64) return;
  int lane =  tid        & 63;
  int nf   = (tid >> 6)  & 3;
  int kk   = (tid >> 8)  & 1;
  int g    = (tid >> 9)  & 15;
  int mat  =  tid >> 13;                 // 0..4
  const float* w = (mat == 0) ? wq : (mat == 1) ? wk : (mat == 2) ? wv : wf;
  float sc = (mat == 0) ? QSCALE : 1.0f;
  int o = nf * 16 + (lane & 15);
  unsigned int packed[4];
  if (mat == 4) {
    // K2 map: elem j <-> k = kk*32 + 4*(lane>>4) + (j&3) + 16*(j>>2)
#pragma unroll
    for (int jj = 0; jj < 4; ++jj) {
      int d0 = kk * 32 + ((jj >> 1) ? 16 : 0) + 4 * (lane >> 4) + 2 * (jj & 1);
      unsigned short lo = f2bf(w[(g * 64 + d0    ) * 64 + o]);
      unsigned short hi = f2bf(w[(g * 64 + d0 + 1) * 64 + o]);
      packed[jj] = (unsigned int)lo | ((unsigned int)hi << 16);
    }
  } else {
    int kb = kk * 32 + 8 * (lane >> 4);
#pragma unroll
    for (int jj = 0; jj < 4; ++jj) {
      unsigned short lo = f2bf(w[(g * 64 + kb + 2 * jj    ) * 64 + o] * sc);
      unsigned short hi = f2bf(w[(g * 64 + kb + 2 * jj + 1) * 64 + o] * sc);
      packed[jj] = (unsigned int)lo | ((unsigned int)hi << 16);
    }
  }
  uint4 u; u.x = packed[0]; u.y = packed[1]; u.z = packed[2]; u.w = packed[3];
  wfrag[tid] = u;
}

// ---------------------------------------------------------------------------
// Phase macros. h_ must be a literal 0/1. All frag temporaries are NAMED
// scalars (no arrays, no ternary-selected lvalues) -> registers guaranteed.
// ---------------------------------------------------------------------------
#define QK_ONE(g_, gi_, nf2_, h_, fwa_, fwb_, bp_, bsc_, dst_) do {           \
  const int nf = 2 * (h_) + (nf2_);                                           \
  float4 b4 = *(const float4*)&(bp_)[(g_) * 64 + nf * 16 + 4 * lq];           \
  f32x4 a1 = {b4.x * (bsc_), b4.y * (bsc_), b4.z * (bsc_), b4.w * (bsc_)};    \
  a1 = __builtin_amdgcn_mfma_f32_16x16x32_bf16((fwa_).v, afr[gi_][0], a1, 0, 0, 0); \
  a1 = __builtin_amdgcn_mfma_f32_16x16x32_bf16((fwb_).v, afr[gi_][1], a1, 0, 0, 0); \
  /* D[o][t]: col t=lr, rows o=nf*16+4lq+r -> d_h = (nf2_)*16+4lq+r */        \
  uint2 w2; w2.x = pk2(a1[0], a1[1]); w2.y = pk2(a1[2], a1[3]);               \
  const int blk = (16 * (2 * (nf2_) + (lq >> 1)) + (g_)) ^ (lr & 7);          \
  *(uint2*)&(dst_)[lr * 512 + blk * 8 + 4 * (lq & 1)] = w2;                   \
} while (0)

#define PH1_MAT(h_, mofs_, bp_, bsc_, dst_) do {                              \
  _Pragma("unroll")                                                           \
  for (int gi = 0; gi < 2; ++gi) {                                            \
    const int g = 2 * w + gi;                                                 \
    FragCast f00, f01, f10, f11;       /* f[kk][nf2], batch-issued */         \
    f00.u4 = wfrag[((((mofs_) + g) * 2 + 0) * 4 + 2 * (h_)    ) * 64 + lane]; \
    f01.u4 = wfrag[((((mofs_) + g) * 2 + 0) * 4 + 2 * (h_) + 1) * 64 + lane]; \
    f10.u4 = wfrag[((((mofs_) + g) * 2 + 1) * 4 + 2 * (h_)    ) * 64 + lane]; \
    f11.u4 = wfrag[((((mofs_) + g) * 2 + 1) * 4 + 2 * (h_) + 1) * 64 + lane]; \
    QK_ONE(g, gi, 0, h_, f00, f10, bp_, bsc_, dst_);                          \
    QK_ONE(g, gi, 1, h_, f01, f11, bp_, bsc_, dst_);                          \
  }                                                                           \
} while (0)

#define PH1_V(h_) do {                                                        \
  _Pragma("unroll")                                                           \
  for (int gi = 0; gi < 2; ++gi) {                                            \
    const int g = 2 * w + gi;                                                 \
    FragCast f00, f01, f10, f11;                                              \
    f00.u4 = wfrag[(((2 * 16 + g) * 2 + 0) * 4 + 2 * (h_)    ) * 64 + lane];  \
    f01.u4 = wfrag[(((2 * 16 + g) * 2 + 0) * 4 + 2 * (h_) + 1) * 64 + lane];  \
    f10.u4 = wfrag[(((2 * 16 + g) * 2 + 1) * 4 + 2 * (h_)    ) * 64 + lane];  \
    f11.u4 = wfrag[(((2 * 16 + g) * 2 + 1) * 4 + 2 * (h_) + 1) * 64 + lane];  \
    const int L = 16 * (g >> 2) + lr;                                         \
    const int jj = g & 3;                                                     \
    {                                                                         \
      const float bias = bv[g * 64 + (2 * (h_)) * 16 + lr];                   \
      f32x4 a1 = {bias, bias, bias, bias};                                    \
      a1 = __builtin_amdgcn_mfma_f32_16x16x32_bf16(afr[gi][0], f00.v, a1, 0, 0, 0); \
      a1 = __builtin_amdgcn_mfma_f32_16x16x32_bf16(afr[gi][1], f10.v, a1, 0, 0, 0); \
      _Pragma("unroll")                                                       \
      for (int r = 0; r < 4; ++r)                                             \
        s_v[((4 * lq + r) * 2 + 0) * 256 + L * 4 + jj] = f2bf(a1[r]);         \
    }                                                                         \
    {                                                                         \
      const float bias = bv[g * 64 + (2 * (h_) + 1) * 16 + lr];               \
      f32x4 a1 = {bias, bias, bias, bias};                                    \
      a1 = __builtin_amdgcn_mfma_f32_16x16x32_bf16(afr[gi][0], f01.v, a1, 0, 0, 0); \
      a1 = __builtin_amdgcn_mfma_f32_16x16x32_bf16(afr[gi][1], f11.v, a1, 0, 0, 0); \
      _Pragma("unroll")                                                       \
      for (int r = 0; r < 4; ++r)                                             \
        s_v[((4 * lq + r) * 2 + 1) * 256 + L * 4 + jj] = f2bf(a1[r]);         \
    }                                                                         \
  }                                                                           \
} while (0)

#define PH1(h_) do {                                                          \
  PH1_MAT(h_, 0,  bq, QSCALE, s_q);                                           \
  PH1_MAT(h_, 16, bk, 1.0f,   s_k);                                           \
  PH1_V(h_);                                                                  \
} while (0)

// PH2: QK^T + softmax + PV. Output either to global att fragment buffer
// (SPLIT) or to s_att (fused).
#define PH2(h_) do {                                                          \
  _Pragma("unroll")                                                           \
  for (int tt = 0; tt < 2; ++tt) {                                            \
    const int t = 2 * w + tt;                                                 \
    f32x4 zero = {0.f, 0.f, 0.f, 0.f};                                        \
    FragCast qa, ka;                                                          \
    const int blk = lane ^ (t & 7);                                           \
    qa.u4 = *(const uint4*)&s_q[t * 512 + blk * 8];                           \
    ka.u4 = *(const uint4*)&s_k[t * 512 + blk * 8];                           \
    /* D[f][g]: col g=lr, rows f=4lq+r (K=32 = full head dim) */              \
    f32x4 sc4 = __builtin_amdgcn_mfma_f32_16x16x32_bf16(ka.v, qa.v, zero, 0, 0, 0); \
    float m = fmaxf(fmaxf(sc4[0], sc4[1]), fmaxf(sc4[2], sc4[3]));            \
    m = fmaxf(m, __shfl_xor(m, 16));                                          \
    m = fmaxf(m, __shfl_xor(m, 32));                                          \
    float p0 = exp2f((sc4[0] - m) * LOG2E);                                   \
    float p1 = exp2f((sc4[1] - m) * LOG2E);                                   \
    float p2 = exp2f((sc4[2] - m) * LOG2E);                                   \
    float p3 = exp2f((sc4[3] - m) * LOG2E);                                   \
    float s = p0 + p1 + p2 + p3;                                              \
    s += __shfl_xor(s, 16);                                                   \
    s += __shfl_xor(s, 32);                                                   \
    const float inv = __fdividef(1.0f, s);                                    \
    FragCast pa;               /* P[g=lr][f=4lq+jj] at slots jj 0..3 */       \
    pa.u[0] = pk2(p0 * inv, p1 * inv);                                        \
    pa.u[1] = pk2(p2 * inv, p3 * inv);                                        \
    pa.u[2] = 0; pa.u[3] = 0;                                                 \
    FragCast va0, va1;         /* V[f=4lq+jj][d=nf*16+lr] at slots jj 0..3 */ \
    va0.u2[0] = *(const uint2*)&s_v[(t * 2 + 0) * 256 + lane * 4];            \
    va0.u[2] = 0; va0.u[3] = 0;                                               \
    va1.u2[0] = *(const uint2*)&s_v[(t * 2 + 1) * 256 + lane * 4];            \
    va1.u[2] = 0; va1.u[3] = 0;                                               \
    /* D[d][g]: col g=lr, rows d=nf*16+4lq+r */                               \
    f32x4 oo0 = __builtin_amdgcn_mfma_f32_16x16x32_bf16(va0.v, pa.v, zero, 0, 0, 0); \
    f32x4 oo1 = __builtin_amdgcn_mfma_f32_16x16x32_bf16(va1.v, pa.v, zero, 0, 0, 0); \
    if constexpr (SPLIT) {                                                    \
      /* att frag for K2: elem j <-> d_h = 4lq+(j&3)+16*(j>>2), row t, g=lr */\
      uint4 u;                                                                \
      u.x = pk2(oo0[0], oo0[1]); u.y = pk2(oo0[2], oo0[3]);                   \
      u.z = pk2(oo1[0], oo1[1]); u.w = pk2(oo1[2], oo1[3]);                   \
      attw[((((int)blockIdx.x * 16 + lr) * 16 + t) * 2 + (h_)) * 4 + lq] = u; \
    } else {                                                                  \
      uint2 w20; w20.x = pk2(oo0[0], oo0[1]); w20.y = pk2(oo0[2], oo0[3]);    \
      const int ab0 = (16 * (0 + (lq >> 1)) + lr) ^ (t & 7);                  \
      *(uint2*)&s_att[t * 512 + ab0 * 8 + 4 * (lq & 1)] = w20;                \
      uint2 w21; w21.x = pk2(oo1[0], oo1[1]); w21.y = pk2(oo1[2], oo1[3]);    \
      const int ab1 = (16 * (2 + (lq >> 1)) + lr) ^ (t & 7);                  \
      *(uint2*)&s_att[t * 512 + ab1 * 8 + 4 * (lq & 1)] = w21;                \
    }                                                                         \
  }                                                                           \
} while (0)

#define PH3(h_) do {                                                          \
  _Pragma("unroll")                                                           \
  for (int gi = 0; gi < 2; ++gi) {                                            \
    const int g = 2 * w + gi;                                                 \
    FragCast aa;               /* att[t=lr][g][d=8lq+j] -> B[k][t] */         \
    const int blk = (16 * lq + g) ^ (lr & 7);                                 \
    aa.u4 = *(const uint4*)&s_att[lr * 512 + blk * 8];                        \
    _Pragma("unroll")                                                         \
    for (int nf = 0; nf < 4; ++nf) {                                          \
      FragCast fc;                                                            \
      fc.u4 = wfrag[(((3 * 16 + g) * 2 + (h_)) * 4 + nf) * 64 + lane];        \
      acc[gi][nf] = __builtin_amdgcn_mfma_f32_16x16x32_bf16(fc.v, aa.v, acc[gi][nf], 0, 0, 0); \
    }                                                                         \
  }                                                                           \
} while (0)

// ---------------------------------------------------------------------------
template <int SPLIT>
__global__ __launch_bounds__(512, 4)
void fused_gc(const float* __restrict__ x,
              const float* __restrict__ bq, const float* __restrict__ bk,
              const float* __restrict__ bv, const float* __restrict__ bfb,
              const uint4* __restrict__ wfrag,
              uint4* __restrict__ attw,
              float* __restrict__ out) {
  // Per-head fragment streams: [t(16)][blk(64)] x 16B; blk = L ^ (t&7).
  __shared__ __align__(16) unsigned short s_q  [16 * 512];
  __shared__ __align__(16) unsigned short s_k  [16 * 512];
  __shared__ __align__(16) unsigned short s_v  [16 * 2 * 64 * 4];
  __shared__ __align__(16) unsigned short s_att[SPLIT ? 16 : 16 * 512];

  const int tid  = threadIdx.x;
  const int w    = tid >> 6;      // 8 waves; g = 2w+gi, t = 2w+tt
  const int lane = tid & 63;
  const int lr   = lane & 15;
  const int lq   = lane >> 4;
  const long tok0 = (long)blockIdx.x * TT;

  // x fragments for this tile: lane's token row = lr
  bf16x8 afr[2][2];
  {
    const float* xr = x + (tok0 + lr) * DM;
#pragma unroll
    for (int gi = 0; gi < 2; ++gi) {
      const int g = 2 * w + gi;
#pragma unroll
      for (int kk = 0; kk < 2; ++kk) {
        const float* p = xr + g * 64 + kk * 32 + 8 * lq;
        afr[gi][kk] = pack8(*(const float4*)p, *(const float4*)(p + 4));
      }
    }
  }

  if constexpr (SPLIT) {
    PH1(0);
    __syncthreads();
    PH2(0);                       // writes att(h0) frags to global
    __syncthreads();              // s_q/k/v reads done before rewrite
    PH1(1);
    __syncthreads();
    PH2(1);
  } else {
    f32x4 acc[2][4];              // [gi][nf] final-linear accumulators
    PH1(0);
    __syncthreads();
    PH2(0);
    __syncthreads();
#pragma unroll
    for (int gi = 0; gi < 2; ++gi) {
      const int g = 2 * w + gi;
#pragma unroll
      for (int nf = 0; nf < 4; ++nf) {
        float4 b4 = *(const float4*)&bfb[g * 64 + nf * 16 + 4 * lq];
        acc[gi][nf][0] = b4.x; acc[gi][nf][1] = b4.y;
        acc[gi][nf][2] = b4.z; acc[gi][nf][3] = b4.w;
      }
    }
    PH3(0);
    PH1(1);
    __syncthreads();
    PH2(1);
    __syncthreads();
    PH3(1);
#pragma unroll
    for (int gi = 0; gi < 2; ++gi) {
      const int g = 2 * w + gi;
#pragma unroll
      for (int nf = 0; nf < 4; ++nf) {
        float4 o4;
        o4.x = acc[gi][nf][0]; o4.y = acc[gi][nf][1];
        o4.z = acc[gi][nf][2]; o4.w = acc[gi][nf][3];
        *(float4*)&out[(tok0 + lr) * DM + g * 64 + nf * 16 + 4 * lq] = o4;
      }
    }
  }
}

// ---------------------------------------------------------------------------
// K2: final grouped linear. Barrier-free, LDS-free, streaming.
// out[o][t] = bias + sum_d wf[g][d][o] * att[t][g][d], per g.
// ---------------------------------------------------------------------------
__global__ __launch_bounds__(512, 2)
void final_gemm(const float* __restrict__ bfb, const uint4* __restrict__ wfrag,
                const uint4* __restrict__ attw, float* __restrict__ out) {
  const int tid  = threadIdx.x;
  const int w    = tid >> 6;
  const int lane = tid & 63;
  const int lr   = lane & 15;
  const int lq   = lane >> 4;
  const long tok0 = (long)blockIdx.x * TT;

#pragma unroll
  for (int gi = 0; gi < 2; ++gi) {
    const int g = 2 * w + gi;
    FragCast fb0, fb1;   // att B-frags, kk = head 0/1
    fb0.u4 = attw[((((int)blockIdx.x * 16 + g) * 16 + lr) * 2 + 0) * 4 + lq];
    fb1.u4 = attw[((((int)blockIdx.x * 16 + g) * 16 + lr) * 2 + 1) * 4 + lq];
#pragma unroll
    for (int nf = 0; nf < 4; ++nf) {
      float4 b4 = *(const float4*)&bfb[g * 64 + nf * 16 + 4 * lq];
      f32x4 a1 = {b4.x, b4.y, b4.z, b4.w};
      FragCast fa0, fa1;  // wf A-frags (mat-4 region, K2 k-map)
      fa0.u4 = wfrag[(((4 * 16 + g) * 2 + 0) * 4 + nf) * 64 + lane];
      fa1.u4 = wfrag[(((4 * 16 + g) * 2 + 1) * 4 + nf) * 64 + lane];
      a1 = __builtin_amdgcn_mfma_f32_16x16x32_bf16(fa0.v, fb0.v, a1, 0, 0, 0);
      a1 = __builtin_amdgcn_mfma_f32_16x16x32_bf16(fa1.v, fb1.v, a1, 0, 0, 0);
      // D[o][t]: col t=lr, rows o=nf*16+4lq+r -> one float4 store
      float4 o4; o4.x = a1[0]; o4.y = a1[1]; o4.z = a1[2]; o4.w = a1[3];
      *(float4*)&out[(tok0 + lr) * DM + g * 64 + nf * 16 + 4 * lq] = o4;
    }
  }
}

// ---------------------------------------------------------------------------
extern "C" void kernel_launch(void* const* d_in, const int* in_sizes, int n_in,
                              void* d_out, int out_size, void* d_ws, size_t ws_size,
                              hipStream_t stream) {
  const float* x   = (const float*)d_in[0];
  const float* wq  = (const float*)d_in[1];
  const float* bq_ = (const float*)d_in[2];
  const float* wk  = (const float*)d_in[3];
  const float* bk_ = (const float*)d_in[4];
  const float* wv  = (const float*)d_in[5];
  const float* bv_ = (const float*)d_in[6];
  const float* wf  = (const float*)d_in[7];
  const float* bf_ = (const float*)d_in[8];
  (void)in_sizes; (void)n_in; (void)out_size;

  uint4* wfrag = (uint4*)d_ws;                      // 5*16*2*4*64 * 16B = 640 KiB
  uint4* attw  = (uint4*)((char*)d_ws + (1u << 20)); // att frags: 128 MiB
  const size_t need = (1u << 20) + (size_t)128 * 1024 * 1024;
  const bool split = (ws_size >= need);

  build_wfrag<<<160, 256, 0, stream>>>(wq, wk, wv, wf, wfrag);
  if (split) {
    fused_gc<1><<<NTOK / TT, 512, 0, stream>>>(x, bq_, bk_, bv_, bf_, wfrag,
                                               attw, (float*)d_out);
    final_gemm<<<NTOK / TT, 512, 0, stream>>>(bf_, wfrag, attw, (float*)d_out);
  } else {
    fused_gc<0><<<NTOK / TT, 512, 0, stream>>>(x, bq_, bk_, bv_, bf_, wfrag,
                                               attw, (float*)d_out);
  }
}

// Round 9
// 192.967 us; speedup vs baseline: 1.7344x; 1.5134x over previous
//
#include <hip/hip_runtime.h>
#include <hip/hip_bf16.h>
#include <stdint.h>

// GroupCommunication fused: 65536 tok x 1024 ch; 16 blocks x 64; 2 heads x 32.
// R9: TT=32 tokens/WG, 1024 thr (16 waves, one g per wave), 160KB dynamic LDS
// (1 WG/CU). Halves weight re-fetch traffic (2048 WGs x 512KB vs R4's 4096)
// and amortizes each weight-frag load over 2 M-tile MFMAs. 4 barriers per 32
// tokens. Layout formulas identical to the verified R8 kernel (rows extended
// to 32 tokens; &7 swizzle keys unaffected by the +16m row offset).
// Schedule: PH1(0) |B| PH2(0)->att0 |B| PH1(1) |B| LOADF+PH2(1)->att1 |B|
//           PH3+store.

typedef __attribute__((ext_vector_type(8))) short bf16x8;
typedef __attribute__((ext_vector_type(4))) float f32x4;

#define NTOK   65536
#define DM     1024
#define TT     32
#define QSCALE 0.17677669529663687f    // 32^-0.5
#define LOG2E  1.4426950408889634f

static __device__ __forceinline__ unsigned short f2bf(float f) {
  union { __hip_bfloat16 h; unsigned short s; } cv;
  cv.h = __float2bfloat16(f);          // RNE
  return cv.s;
}

static __device__ __forceinline__ unsigned int pk2(float a, float b) {
  return (unsigned int)f2bf(a) | ((unsigned int)f2bf(b) << 16);
}

static __device__ __forceinline__ bf16x8 pack8(float4 a, float4 b) {
  bf16x8 r;
  r[0] = (short)f2bf(a.x); r[1] = (short)f2bf(a.y);
  r[2] = (short)f2bf(a.z); r[3] = (short)f2bf(a.w);
  r[4] = (short)f2bf(b.x); r[5] = (short)f2bf(b.y);
  r[6] = (short)f2bf(b.z); r[7] = (short)f2bf(b.w);
  return r;
}

union FragCast { uint4 u4; bf16x8 v; uint2 u2[2]; unsigned int u[4]; };

// ---------------------------------------------------------------------------
// Prologue: pack wq(scaled),wk,wv,wf fp32 [g][i][o] -> bf16 fragment stream.
// frag elem j = W[k = kk*32 + 8*(lane>>4) + j][o = nf*16 + (lane&15)].
// A- and B-side consumers always use the identical (lane,j)->k map.
// ---------------------------------------------------------------------------
__global__ void build_wfrag(const float* __restrict__ wq, const float* __restrict__ wk,
                            const float* __restrict__ wv, const float* __restrict__ wf,
                            uint4* __restrict__ wfrag) {
  int tid = blockIdx.x * 256 + threadIdx.x;
  if (tid >= 4 * 16 * 2 * 4 * 64) return;
  int lane =  tid        & 63;
  int nf   = (tid >> 6)  & 3;
  int kk   = (tid >> 8)  & 1;
  int g    = (tid >> 9)  & 15;
  int mat  =  tid >> 13;
  const float* w = (mat == 0) ? wq : (mat == 1) ? wk : (mat == 2) ? wv : wf;
  float sc = (mat == 0) ? QSCALE : 1.0f;
  int o  = nf * 16 + (lane & 15);
  int kb = kk * 32 + 8 * (lane >> 4);
  unsigned int packed[4];
#pragma unroll
  for (int jj = 0; jj < 4; ++jj) {
    unsigned short lo = f2bf(w[(g * 64 + kb + 2 * jj    ) * 64 + o] * sc);
    unsigned short hi = f2bf(w[(g * 64 + kb + 2 * jj + 1) * 64 + o] * sc);
    packed[jj] = (unsigned int)lo | ((unsigned int)hi << 16);
  }
  uint4 u; u.x = packed[0]; u.y = packed[1]; u.z = packed[2]; u.w = packed[3];
  wfrag[tid] = u;
}

// ---------------------------------------------------------------------------
// Phase helper macros (h_ / nf2_ literals; named frags only -> registers).
// ---------------------------------------------------------------------------

// q/k: swapped orientation. D[o][t]: col t = lr (token 16m+lr), rows
// o = nf*16+4lq+r. One weight frag pair feeds both M-tiles.
#define QK_STORE(fA_, fB_, nf2_, h_, bp_, bsc_, dst_) do {                    \
  const int nf = 2 * (h_) + (nf2_);                                           \
  float4 b4 = *(const float4*)&(bp_)[g * 64 + nf * 16 + 4 * lq];              \
  _Pragma("unroll")                                                           \
  for (int m = 0; m < 2; ++m) {                                               \
    f32x4 a1 = {b4.x * (bsc_), b4.y * (bsc_), b4.z * (bsc_), b4.w * (bsc_)};  \
    a1 = __builtin_amdgcn_mfma_f32_16x16x32_bf16((fA_).v, afr[m][0], a1, 0, 0, 0); \
    a1 = __builtin_amdgcn_mfma_f32_16x16x32_bf16((fB_).v, afr[m][1], a1, 0, 0, 0); \
    uint2 w2; w2.x = pk2(a1[0], a1[1]); w2.y = pk2(a1[2], a1[3]);             \
    const int blk = (16 * (2 * (nf2_) + (lq >> 1)) + g) ^ (lr & 7);           \
    *(uint2*)&(dst_)[(16 * m + lr) * 512 + blk * 8 + 4 * (lq & 1)] = w2;      \
  }                                                                           \
} while (0)

// v: original orientation. D[t][o]: rows t = 16m+4lq+r, col d_h = nf2*16+lr;
// stream pos encodes (f=g, d): pos = 64*(g>>2) + 4*d + (g&3).
#define V_STORE(fA_, fB_, nf2_, h_) do {                                      \
  const int nf = 2 * (h_) + (nf2_);                                           \
  const float bias = bv[g * 64 + nf * 16 + lr];                               \
  const int L = 16 * (g >> 2) + lr;                                           \
  const int jj = g & 3;                                                       \
  _Pragma("unroll")                                                           \
  for (int m = 0; m < 2; ++m) {                                               \
    f32x4 a1 = {bias, bias, bias, bias};                                      \
    a1 = __builtin_amdgcn_mfma_f32_16x16x32_bf16(afr[m][0], (fA_).v, a1, 0, 0, 0); \
    a1 = __builtin_amdgcn_mfma_f32_16x16x32_bf16(afr[m][1], (fB_).v, a1, 0, 0, 0); \
    _Pragma("unroll")                                                         \
    for (int r = 0; r < 4; ++r)                                               \
      s_v[((16 * m + 4 * lq + r) * 2 + (nf2_)) * 256 + L * 4 + jj] = f2bf(a1[r]); \
  }                                                                           \
} while (0)

#define PH1(h_) do {                                                          \
  FragCast q0a, q0b, q1a, q1b, k0a, k0b, k1a, k1b, v0a, v0b, v1a, v1b;        \
  q0a.u4 = wfrag[(((0 * 16 + g) * 2 + 0) * 4 + 2 * (h_)    ) * 64 + lane];    \
  q0b.u4 = wfrag[(((0 * 16 + g) * 2 + 1) * 4 + 2 * (h_)    ) * 64 + lane];    \
  q1a.u4 = wfrag[(((0 * 16 + g) * 2 + 0) * 4 + 2 * (h_) + 1) * 64 + lane];    \
  q1b.u4 = wfrag[(((0 * 16 + g) * 2 + 1) * 4 + 2 * (h_) + 1) * 64 + lane];    \
  k0a.u4 = wfrag[(((1 * 16 + g) * 2 + 0) * 4 + 2 * (h_)    ) * 64 + lane];    \
  k0b.u4 = wfrag[(((1 * 16 + g) * 2 + 1) * 4 + 2 * (h_)    ) * 64 + lane];    \
  k1a.u4 = wfrag[(((1 * 16 + g) * 2 + 0) * 4 + 2 * (h_) + 1) * 64 + lane];    \
  k1b.u4 = wfrag[(((1 * 16 + g) * 2 + 1) * 4 + 2 * (h_) + 1) * 64 + lane];    \
  v0a.u4 = wfrag[(((2 * 16 + g) * 2 + 0) * 4 + 2 * (h_)    ) * 64 + lane];    \
  v0b.u4 = wfrag[(((2 * 16 + g) * 2 + 1) * 4 + 2 * (h_)    ) * 64 + lane];    \
  v1a.u4 = wfrag[(((2 * 16 + g) * 2 + 0) * 4 + 2 * (h_) + 1) * 64 + lane];    \
  v1b.u4 = wfrag[(((2 * 16 + g) * 2 + 1) * 4 + 2 * (h_) + 1) * 64 + lane];    \
  QK_STORE(q0a, q0b, 0, h_, bq, QSCALE, s_q);                                 \
  QK_STORE(q1a, q1b, 1, h_, bq, QSCALE, s_q);                                 \
  QK_STORE(k0a, k0b, 0, h_, bk, 1.0f,   s_k);                                 \
  QK_STORE(k1a, k1b, 1, h_, bk, 1.0f,   s_k);                                 \
  V_STORE(v0a, v0b, 0, h_);                                                   \
  V_STORE(v1a, v1b, 1, h_);                                                   \
} while (0)

// PH2: QK^T + softmax + PV for t = g and t = g+16 of the current head.
#define PH2(ATT_) do {                                                        \
  _Pragma("unroll")                                                           \
  for (int tt = 0; tt < 2; ++tt) {                                            \
    const int t = g + 16 * tt;                                                \
    f32x4 zero = {0.f, 0.f, 0.f, 0.f};                                        \
    FragCast qa, ka;                                                          \
    const int blk = lane ^ (t & 7);                                           \
    qa.u4 = *(const uint4*)&s_q[t * 512 + blk * 8];                           \
    ka.u4 = *(const uint4*)&s_k[t * 512 + blk * 8];                           \
    /* D[f][g]: col g=lr, rows f=4lq+r (K=32 = full head dim) */              \
    f32x4 sc4 = __builtin_amdgcn_mfma_f32_16x16x32_bf16(ka.v, qa.v, zero, 0, 0, 0); \
    float m = fmaxf(fmaxf(sc4[0], sc4[1]), fmaxf(sc4[2], sc4[3]));            \
    m = fmaxf(m, __shfl_xor(m, 16));                                          \
    m = fmaxf(m, __shfl_xor(m, 32));                                          \
    float p0 = exp2f((sc4[0] - m) * LOG2E);                                   \
    float p1 = exp2f((sc4[1] - m) * LOG2E);                                   \
    float p2 = exp2f((sc4[2] - m) * LOG2E);                                   \
    float p3 = exp2f((sc4[3] - m) * LOG2E);                                   \
    float s = p0 + p1 + p2 + p3;                                              \
    s += __shfl_xor(s, 16);                                                   \
    s += __shfl_xor(s, 32);                                                   \
    const float inv = __fdividef(1.0f, s);                                    \
    FragCast pa;               /* P[g=lr][f=4lq+jj] at slots jj 0..3 */       \
    pa.u[0] = pk2(p0 * inv, p1 * inv);                                        \
    pa.u[1] = pk2(p2 * inv, p3 * inv);                                        \
    pa.u[2] = 0; pa.u[3] = 0;                                                 \
    FragCast va0, va1;         /* V[f=4lq+jj][d=nf*16+lr] at slots jj 0..3 */ \
    va0.u2[0] = *(const uint2*)&s_v[(t * 2 + 0) * 256 + lane * 4];            \
    va0.u[2] = 0; va0.u[3] = 0;                                               \
    va1.u2[0] = *(const uint2*)&s_v[(t * 2 + 1) * 256 + lane * 4];            \
    va1.u[2] = 0; va1.u[3] = 0;                                               \
    /* D[d][g]: col g=lr, rows d=nf*16+4lq+r */                               \
    f32x4 oo0 = __builtin_amdgcn_mfma_f32_16x16x32_bf16(va0.v, pa.v, zero, 0, 0, 0); \
    f32x4 oo1 = __builtin_amdgcn_mfma_f32_16x16x32_bf16(va1.v, pa.v, zero, 0, 0, 0); \
    uint2 w20; w20.x = pk2(oo0[0], oo0[1]); w20.y = pk2(oo0[2], oo0[3]);      \
    const int ab0 = (16 * (0 + (lq >> 1)) + lr) ^ (t & 7);                    \
    *(uint2*)&(ATT_)[t * 512 + ab0 * 8 + 4 * (lq & 1)] = w20;                 \
    uint2 w21; w21.x = pk2(oo1[0], oo1[1]); w21.y = pk2(oo1[2], oo1[3]);      \
    const int ab1 = (16 * (2 + (lq >> 1)) + lr) ^ (t & 7);                    \
    *(uint2*)&(ATT_)[t * 512 + ab1 * 8 + 4 * (lq & 1)] = w21;                 \
  }                                                                           \
} while (0)

#define LOADF() do {                                                          \
  f0n0.u4 = wfrag[(((3 * 16 + g) * 2 + 0) * 4 + 0) * 64 + lane];              \
  f0n1.u4 = wfrag[(((3 * 16 + g) * 2 + 0) * 4 + 1) * 64 + lane];              \
  f0n2.u4 = wfrag[(((3 * 16 + g) * 2 + 0) * 4 + 2) * 64 + lane];              \
  f0n3.u4 = wfrag[(((3 * 16 + g) * 2 + 0) * 4 + 3) * 64 + lane];              \
  f1n0.u4 = wfrag[(((3 * 16 + g) * 2 + 1) * 4 + 0) * 64 + lane];              \
  f1n1.u4 = wfrag[(((3 * 16 + g) * 2 + 1) * 4 + 1) * 64 + lane];              \
  f1n2.u4 = wfrag[(((3 * 16 + g) * 2 + 1) * 4 + 2) * 64 + lane];              \
  f1n3.u4 = wfrag[(((3 * 16 + g) * 2 + 1) * 4 + 3) * 64 + lane];              \
} while (0)

#define PH3_NF(f0_, f1_, nf_, m_, aa0_, aa1_) do {                            \
  float4 b4 = *(const float4*)&bfb[g * 64 + (nf_) * 16 + 4 * lq];             \
  f32x4 a1 = {b4.x, b4.y, b4.z, b4.w};                                        \
  a1 = __builtin_amdgcn_mfma_f32_16x16x32_bf16((f0_).v, (aa0_).v, a1, 0, 0, 0); \
  a1 = __builtin_amdgcn_mfma_f32_16x16x32_bf16((f1_).v, (aa1_).v, a1, 0, 0, 0); \
  float4 o4; o4.x = a1[0]; o4.y = a1[1]; o4.z = a1[2]; o4.w = a1[3];          \
  *(float4*)&out[(tok0 + 16 * (m_) + lr) * DM + g * 64 + (nf_) * 16 + 4 * lq] = o4; \
} while (0)

#define PH3() do {                                                            \
  const int blk3 = (16 * lq + g) ^ (lr & 7);                                  \
  _Pragma("unroll")                                                           \
  for (int m = 0; m < 2; ++m) {                                               \
    FragCast aa0, aa1;         /* att[t=16m+lr][g][d_h=8lq+j], per head */    \
    aa0.u4 = *(const uint4*)&s_a0[(16 * m + lr) * 512 + blk3 * 8];            \
    aa1.u4 = *(const uint4*)&s_a1[(16 * m + lr) * 512 + blk3 * 8];            \
    PH3_NF(f0n0, f1n0, 0, m, aa0, aa1);                                       \
    PH3_NF(f0n1, f1n1, 1, m, aa0, aa1);                                       \
    PH3_NF(f0n2, f1n2, 2, m, aa0, aa1);                                       \
    PH3_NF(f0n3, f1n3, 3, m, aa0, aa1);                                       \
  }                                                                           \
} while (0)

// ---------------------------------------------------------------------------
__global__ __launch_bounds__(1024)
void fused_gc32(const float* __restrict__ x,
                const float* __restrict__ bq, const float* __restrict__ bk,
                const float* __restrict__ bv, const float* __restrict__ bfb,
                const uint4* __restrict__ wfrag,
                float* __restrict__ out) {
  // Dynamic LDS, 160KB: five 32KB buffers.
  // q/k/att: [t(32)][blk(64)] x 16B, blk key ^(t&7).
  // v: [(t*2+nf2)][256 shorts] stream, pos = 64*(g>>2)+4*d+(g&3).
  extern __shared__ __align__(16) unsigned short sm[];
  unsigned short* const s_q  = sm;
  unsigned short* const s_k  = sm + 16384;
  unsigned short* const s_v  = sm + 32768;
  unsigned short* const s_a0 = sm + 49152;
  unsigned short* const s_a1 = sm + 65536;

  const int tid  = threadIdx.x;
  const int g    = tid >> 6;      // 16 waves: wave = g (PH1/PH3), t-base (PH2)
  const int lane = tid & 63;
  const int lr   = lane & 15;
  const int lq   = lane >> 4;
  const long tok0 = (long)blockIdx.x * TT;

  // x fragments: token rows 16m+lr
  bf16x8 afr[2][2];
#pragma unroll
  for (int m = 0; m < 2; ++m) {
    const float* xr = x + (tok0 + 16 * m + lr) * DM + g * 64;
#pragma unroll
    for (int kk = 0; kk < 2; ++kk) {
      const float* p = xr + kk * 32 + 8 * lq;
      afr[m][kk] = pack8(*(const float4*)p, *(const float4*)(p + 4));
    }
  }

  FragCast f0n0, f0n1, f0n2, f0n3, f1n0, f1n1, f1n2, f1n3;  // PH3 weights

  PH1(0);
  __syncthreads();
  PH2(s_a0);
  __syncthreads();
  PH1(1);
  __syncthreads();
  LOADF();                        // f-frags hide under PH2(1)
  PH2(s_a1);
  __syncthreads();
  PH3();
}

// ---------------------------------------------------------------------------
extern "C" void kernel_launch(void* const* d_in, const int* in_sizes, int n_in,
                              void* d_out, int out_size, void* d_ws, size_t ws_size,
                              hipStream_t stream) {
  const float* x   = (const float*)d_in[0];
  const float* wq  = (const float*)d_in[1];
  const float* bq_ = (const float*)d_in[2];
  const float* wk  = (const float*)d_in[3];
  const float* bk_ = (const float*)d_in[4];
  const float* wv  = (const float*)d_in[5];
  const float* bv_ = (const float*)d_in[6];
  const float* wf  = (const float*)d_in[7];
  const float* bf_ = (const float*)d_in[8];
  (void)in_sizes; (void)n_in; (void)out_size; (void)ws_size;

  uint4* wfrag = (uint4*)d_ws;   // 4*16*2*4*64 frags * 16B = 512 KiB

  static_assert(sizeof(unsigned short) == 2, "");
  const int lds_bytes = 5 * 32 * 1024;   // 160 KB
  hipFuncSetAttribute(reinterpret_cast<const void*>(fused_gc32),
                      hipFuncAttributeMaxDynamicSharedMemorySize, lds_bytes);

  build_wfrag<<<128, 256, 0, stream>>>(wq, wk, wv, wf, wfrag);
  fused_gc32<<<NTOK / TT, 1024, lds_bytes, stream>>>(x, bq_, bk_, bv_, bf_,
                                                     wfrag, (float*)d_out);
}